// Round 9
// baseline (273.376 us; speedup 1.0000x reference)
//
#include <hip/hip_runtime.h>
#include <math.h>

// DTW loss: B=128, L1=L2=512, D=16.
// R9: systolic single wave per batch (lane j owns cols 8j..8j+7, step s
// processes row i=s-j). Changes vs R8:
//  - y-tile + x prefetch loaded VOLATILE: LLVM cannot remat/split/sink
//    volatile accesses -> y2 stays in 128 VGPRs, prefetch stays 1 step ahead
//  - pv init +inf, fill-phase handled by poisoning x.sq (1 cndmask) instead
//    of 8 freeze-cndmasks; drain needs no guard (loop stops at s=574)
//  - y pre-scaled by -2, dot accumulator seeded with {ysq,0}

#define TL 512
#define TD 16
#define TNB 128
#define BIGF 3.0e38f
#define INFF __builtin_inff()
#define XSTR 20   // floats per padded LDS row (80 B)

typedef float f32x2 __attribute__((ext_vector_type(2)));
typedef float f32x4 __attribute__((ext_vector_type(4)));

__device__ inline f32x2 pk_fma(f32x2 a, f32x2 b, f32x2 c) {
    f32x2 d;
    asm("v_pk_fma_f32 %0, %1, %2, %3" : "=v"(d) : "v"(a), "v"(b), "v"(c));
    return d;
}
__device__ inline f32x2 pk_mul(f32x2 a, f32x2 b) {
    f32x2 d;
    asm("v_pk_mul_f32 %0, %1, %2" : "=v"(d) : "v"(a), "v"(b));
    return d;
}
__device__ inline float min3f(float a, float b, float c) {
    float d;
    asm("v_min3_f32 %0, %1, %2, %3" : "=v"(d) : "v"(a), "v"(b), "v"(c));
    return d;
}
template<int CTRL, int RM, bool BC>
__device__ inline float dpp_mov(float old_, float src) {
    return __int_as_float(__builtin_amdgcn_update_dpp(
        __float_as_int(old_), __float_as_int(src), CTRL, RM, 0xf, BC));
}

struct XR { f32x4 q0, q1, q2, q3; float sq; };

__device__ inline void issue_load(const float* __restrict__ xlds, int s, int t, XR& d) {
    int i = s - t;
    i = i < 0 ? 0 : i;
    i = i > TL - 1 ? TL - 1 : i;                 // clamp; garbage is shielded
    const volatile f32x4* p = (const volatile f32x4*)(xlds + i * XSTR);
    d.q0 = p[0]; d.q1 = p[1]; d.q2 = p[2]; d.q3 = p[3];
    d.sq = ((const volatile float*)(xlds + i * XSTR))[16];
}

__device__ inline void step(const XR& x, const f32x2 (&y2s)[8][8], const f32x2 (&ysqv)[8],
                            float (&pv)[8], float& o7, float sd, int s, int t) {
    const float sq = (t > s) ? BIGF : x.sq;      // poison during pipeline fill
    f32x2 xp[8];
    xp[0] = f32x2{x.q0.x, x.q0.y}; xp[1] = f32x2{x.q0.z, x.q0.w};
    xp[2] = f32x2{x.q1.x, x.q1.y}; xp[3] = f32x2{x.q1.z, x.q1.w};
    xp[4] = f32x2{x.q2.x, x.q2.y}; xp[5] = f32x2{x.q2.z, x.q2.w};
    xp[6] = f32x2{x.q3.x, x.q3.y}; xp[7] = f32x2{x.q3.z, x.q3.w};

    float cc[8];
    #pragma unroll
    for (int k = 0; k < 8; ++k) {
        f32x2 acc = ysqv[k];                     // {ysq, 0}
        #pragma unroll
        for (int p = 0; p < 8; ++p) acc = pk_fma(xp[p], y2s[k][p], acc);  // y2s = -2y
        cc[k] = sq + (acc.x + acc.y);
    }

    const float left = dpp_mov<0x138, 0xf, false>(BIGF, pv[7]);  // DTW[i][8t-1]
    const float diag = dpp_mov<0x138, 0xf, false>(sd,   o7);     // DTW[i-1][8t-1]
    o7 = pv[7];

    float v[8];
    v[0] = cc[0] + min3f(pv[0], left, diag);
    #pragma unroll
    for (int k = 1; k < 8; ++k)
        v[k] = cc[k] + min3f(pv[k], v[k - 1], pv[k - 1]);
    #pragma unroll
    for (int k = 0; k < 8; ++k) pv[k] = v[k];
}

__global__ __launch_bounds__(64, 1) void dtw_systolic_kernel(const float* __restrict__ s1,
                                                             const float* __restrict__ s2,
                                                             float* __restrict__ ws) {
    const int b = blockIdx.x;
    const int t = threadIdx.x;   // lane 0..63

    __shared__ float xlds[TL * XSTR];   // 40 KB padded s1 copy (sq at [16])

    const float* s1b = s1 + (size_t)b * TL * TD;

    // stage s1 -> LDS (stride 20) + row sumsq; 8 rows per lane
    #pragma unroll
    for (int k8 = 0; k8 < 8; ++k8) {
        const int r = t + 64 * k8;
        const f32x4* src = (const f32x4*)(s1b + r * TD);
        f32x4 q0 = src[0], q1 = src[1], q2 = src[2], q3 = src[3];
        f32x4* dst = (f32x4*)(xlds + r * XSTR);
        dst[0] = q0; dst[1] = q1; dst[2] = q2; dst[3] = q3;
        f32x2 a_ = pk_mul(f32x2{q0.x, q0.y}, f32x2{q0.x, q0.y});
        a_ = pk_fma(f32x2{q0.z, q0.w}, f32x2{q0.z, q0.w}, a_);
        a_ = pk_fma(f32x2{q1.x, q1.y}, f32x2{q1.x, q1.y}, a_);
        a_ = pk_fma(f32x2{q1.z, q1.w}, f32x2{q1.z, q1.w}, a_);
        a_ = pk_fma(f32x2{q2.x, q2.y}, f32x2{q2.x, q2.y}, a_);
        a_ = pk_fma(f32x2{q2.z, q2.w}, f32x2{q2.z, q2.w}, a_);
        a_ = pk_fma(f32x2{q3.x, q3.y}, f32x2{q3.x, q3.y}, a_);
        a_ = pk_fma(f32x2{q3.z, q3.w}, f32x2{q3.z, q3.w}, a_);
        xlds[r * XSTR + 16] = a_.x + a_.y;
    }

    // y tile: volatile loads (remat-proof), then ysq + scale by -2
    const float* s2b = s2 + ((size_t)b * TL + 8 * (size_t)t) * TD;
    f32x2 y2s[8][8];
    #pragma unroll
    for (int k = 0; k < 8; ++k) {
        #pragma unroll
        for (int p = 0; p < 8; ++p)
            y2s[k][p] = *(const volatile f32x2*)(s2b + k * TD + 2 * p);
    }
    f32x2 ysqv[8];
    #pragma unroll
    for (int k = 0; k < 8; ++k) {
        f32x2 acc = pk_mul(y2s[k][0], y2s[k][0]);
        #pragma unroll
        for (int p = 1; p < 8; ++p) acc = pk_fma(y2s[k][p], y2s[k][p], acc);
        ysqv[k] = f32x2{acc.x + acc.y, 0.f};
        #pragma unroll
        for (int p = 0; p < 8; ++p) y2s[k][p] = pk_mul(y2s[k][p], f32x2{-2.f, -2.f});
    }

    __syncthreads();   // drain LDS staging (single wave)

    float pv[8];
    #pragma unroll
    for (int k = 0; k < 8; ++k) pv[k] = INFF;
    float o7 = INFF;

    XR xa, xb;
    issue_load(xlds, 0, t, xa);
    issue_load(xlds, 1, t, xb);

    step(xa, y2s, ysqv, pv, o7, 0.0f, 0, t);    // s = 0 (diag seed = 0)

    for (int p = 0; p < 287; ++p) {              // steps s = 1 .. 574
        const int s = 2 * p + 1;
        issue_load(xlds, s + 1, t, xa);
        step(xb, y2s, ysqv, pv, o7, BIGF, s, t);
        issue_load(xlds, s + 2, t, xb);
        step(xa, y2s, ysqv, pv, o7, BIGF, s + 1, t);
    }
    // lane 63's last valid update is s=574 (row 511); no drain corruption

    if (t == 63) ws[b] = sqrtf(pv[7]);
}

__global__ void dtw_reduce_kernel(const float* __restrict__ ws, float* __restrict__ out) {
    const int t = threadIdx.x;          // 64 threads
    float v = ws[t] + ws[t + 64];
    #pragma unroll
    for (int d2 = 32; d2 > 0; d2 >>= 1) v += __shfl_down(v, d2);
    if (t == 0) out[0] = v * (1.0f / TNB);
}

extern "C" void kernel_launch(void* const* d_in, const int* in_sizes, int n_in,
                              void* d_out, int out_size, void* d_ws, size_t ws_size,
                              hipStream_t stream) {
    const float* s1 = (const float*)d_in[0];
    const float* s2 = (const float*)d_in[1];
    float* ws  = (float*)d_ws;
    float* out = (float*)d_out;

    dtw_systolic_kernel<<<TNB, 64, 0, stream>>>(s1, s2, ws);
    dtw_reduce_kernel<<<1, 64, 0, stream>>>(ws, out);
}

// Round 10
// 117.436 us; speedup vs baseline: 2.3279x; 2.3279x over previous
//
#include <hip/hip_runtime.h>
#include <math.h>

// DTW loss: B=128, L1=L2=512, D=16.
// R10: 4-wave column-split skewed systolic. Block = 256 threads (4 waves),
// one block per batch. Global lane L = 67*W + l owns cols {2*(64W+l), +1}
// (y tile = 32 VGPRs). At epoch e, sub-step m (4 sub-steps/epoch), lane
// processes row r = 4e+m-L: 2 cells (min3+add), left/diag via wave_shr DPP.
// Cross-wave boundary handed off as a 4-row packet in LDS, one barrier per
// epoch (194 total). Wave offset 67=64+3 keeps the producer packet one epoch
// ahead. x rows from stride-18 LDS copy (b64 reads); invalid rows poisoned
// via sq=BIG (R9-verified); pv init +inf; seed DTW[-1][-1]=0 via carry.

#define TL 512
#define TD 16
#define TNB 128
#define BIGF 3.0e38f
#define INFF __builtin_inff()
#define XSTR 18
#define WOFF 67
#define NE 194

typedef float f32x2 __attribute__((ext_vector_type(2)));
typedef float f32x4 __attribute__((ext_vector_type(4)));

__device__ inline f32x2 pk_fma(f32x2 a, f32x2 b, f32x2 c) {
    f32x2 d;
    asm("v_pk_fma_f32 %0, %1, %2, %3" : "=v"(d) : "v"(a), "v"(b), "v"(c));
    return d;
}
__device__ inline f32x2 pk_mul(f32x2 a, f32x2 b) {
    f32x2 d;
    asm("v_pk_mul_f32 %0, %1, %2" : "=v"(d) : "v"(a), "v"(b));
    return d;
}
__device__ inline float min3f(float a, float b, float c) {
    float d;
    asm("v_min3_f32 %0, %1, %2, %3" : "=v"(d) : "v"(a), "v"(b), "v"(c));
    return d;
}
template<int CTRL, int RM, bool BC>
__device__ inline float dpp_mov(float old_, float src) {
    return __int_as_float(__builtin_amdgcn_update_dpp(
        __float_as_int(old_), __float_as_int(src), CTRL, RM, 0xf, BC));
}

struct XR { f32x2 d[8]; float sq; };

__device__ inline void xload(const float* __restrict__ xlds, int r, XR& x) {
    int rc = r < 0 ? 0 : (r > TL - 1 ? TL - 1 : r);   // clamp; shielded by BIG
    const float* p = xlds + rc * XSTR;
    #pragma unroll
    for (int k = 0; k < 8; ++k) x.d[k] = *(const f32x2*)(p + 2 * k);
    x.sq = p[16];
}

// one systolic sub-step: 2 cells (cols j0, j0+1) of row r
__device__ inline void substep(const XR& x, bool valid,
                               const f32x2 (&y0)[8], const f32x2 (&y1)[8],
                               f32x2 ys0, f32x2 ys1,
                               float& pv0, float& pv1, float& o1,
                               float bLeft, float bDiag, bool lane0) {
    const float sq = valid ? x.sq : BIGF;
    f32x2 a0 = ys0, a1 = ys1;        // {ysq, 0}; y pre-scaled by -2
    #pragma unroll
    for (int k = 0; k < 8; ++k) {
        a0 = pk_fma(x.d[k], y0[k], a0);
        a1 = pk_fma(x.d[k], y1[k], a1);
    }
    const float c0 = sq + (a0.x + a0.y);
    const float c1 = sq + (a1.x + a1.y);

    float left = dpp_mov<0x138, 0xf, false>(BIGF, pv1);  // lane-1: DTW[r][j0-1]
    float diag = dpp_mov<0x138, 0xf, false>(BIGF, o1);   // lane-1: DTW[r-1][j0-1]
    if (lane0) { left = bLeft; diag = bDiag; }
    o1 = pv1;                                            // pre-update

    const float v0 = c0 + min3f(pv0, left, diag);
    const float v1 = c1 + min3f(pv1, v0, pv0);
    pv0 = v0; pv1 = v1;
}

__global__ __launch_bounds__(256, 1) void dtw_split_kernel(const float* __restrict__ s1,
                                                           const float* __restrict__ s2,
                                                           float* __restrict__ ws) {
    const int b   = blockIdx.x;
    const int tid = threadIdx.x;
    const int W   = tid >> 6;    // wave 0..3
    const int l   = tid & 63;

    __shared__ float xlds[TL * XSTR];   // 36,864 B: 16 floats + sq per row
    __shared__ float pkt[2][4][4];      // 128 B boundary packets

    const float* s1b = s1 + (size_t)b * TL * TD;

    // stage s1 rows (2 per thread) + row sumsq
    #pragma unroll
    for (int q = 0; q < 2; ++q) {
        const int r = 2 * tid + q;
        const f32x4* src = (const f32x4*)(s1b + r * TD);
        f32x4 q0 = src[0], q1 = src[1], q2 = src[2], q3 = src[3];
        float* dst = xlds + r * XSTR;
        *(f32x2*)(dst + 0)  = f32x2{q0.x, q0.y};
        *(f32x2*)(dst + 2)  = f32x2{q0.z, q0.w};
        *(f32x2*)(dst + 4)  = f32x2{q1.x, q1.y};
        *(f32x2*)(dst + 6)  = f32x2{q1.z, q1.w};
        *(f32x2*)(dst + 8)  = f32x2{q2.x, q2.y};
        *(f32x2*)(dst + 10) = f32x2{q2.z, q2.w};
        *(f32x2*)(dst + 12) = f32x2{q3.x, q3.y};
        *(f32x2*)(dst + 14) = f32x2{q3.z, q3.w};
        f32x2 a_ = pk_mul(f32x2{q0.x, q0.y}, f32x2{q0.x, q0.y});
        a_ = pk_fma(f32x2{q0.z, q0.w}, f32x2{q0.z, q0.w}, a_);
        a_ = pk_fma(f32x2{q1.x, q1.y}, f32x2{q1.x, q1.y}, a_);
        a_ = pk_fma(f32x2{q1.z, q1.w}, f32x2{q1.z, q1.w}, a_);
        a_ = pk_fma(f32x2{q2.x, q2.y}, f32x2{q2.x, q2.y}, a_);
        a_ = pk_fma(f32x2{q2.z, q2.w}, f32x2{q2.z, q2.w}, a_);
        a_ = pk_fma(f32x2{q3.x, q3.y}, f32x2{q3.x, q3.y}, a_);
        a_ = pk_fma(f32x2{q3.z, q3.w}, f32x2{q3.z, q3.w}, a_);
        dst[16] = a_.x + a_.y;
    }
    if (tid < 32) ((float*)pkt)[tid] = BIGF;

    // y tile: 2 cols/lane resident; prescale by -2; acc seeds {ysq, 0}
    const int j0 = 2 * (64 * W + l);
    f32x2 y0[8], y1[8];
    const float* yp0 = s2 + ((size_t)b * TL + j0) * TD;
    #pragma unroll
    for (int k = 0; k < 8; ++k) {
        y0[k] = *(const f32x2*)(yp0 + 2 * k);
        y1[k] = *(const f32x2*)(yp0 + TD + 2 * k);
    }
    f32x2 s0a = pk_mul(y0[0], y0[0]), s1a = pk_mul(y1[0], y1[0]);
    #pragma unroll
    for (int k = 1; k < 8; ++k) {
        s0a = pk_fma(y0[k], y0[k], s0a);
        s1a = pk_fma(y1[k], y1[k], s1a);
    }
    const f32x2 ys0 = {s0a.x + s0a.y, 0.f};
    const f32x2 ys1 = {s1a.x + s1a.y, 0.f};
    #pragma unroll
    for (int k = 0; k < 8; ++k) {
        y0[k] = pk_mul(y0[k], f32x2{-2.f, -2.f});
        y1[k] = pk_mul(y1[k], f32x2{-2.f, -2.f});
    }

    __syncthreads();

    const int gL = WOFF * W + l;
    float pv0 = INFF, pv1 = INFF, o1 = INFF;
    float carry = (W == 0) ? 0.f : BIGF;   // diag seed DTW[-1][-1]=0 (W0 lane0)
    const bool lane0 = (l == 0);

    XR xa, xb;
    xload(xlds, -gL, xa);   // row for e=0, m=0

    for (int e = 0; e < NE; ++e) {
        // boundary packet from wave W-1 (written at epoch e-1, parity (e-1)&1)
        float l0 = BIGF, l1 = BIGF, l2 = BIGF, l3 = BIGF;
        if (W > 0) {
            f32x4 p = *(const f32x4*)&pkt[(e + 1) & 1][W - 1][0];
            l0 = p.x; l1 = p.y; l2 = p.z; l3 = p.w;
        }

        const int rbase = 4 * e - gL;
        float t0, t1, t2, t3;   // pv1 after each sub-step (for the packet)

        xload(xlds, rbase + 1, xb);
        substep(xa, (unsigned)(rbase + 0) < (unsigned)TL, y0, y1, ys0, ys1,
                pv0, pv1, o1, l0, carry, lane0);
        t0 = pv1;

        xload(xlds, rbase + 2, xa);
        substep(xb, (unsigned)(rbase + 1) < (unsigned)TL, y0, y1, ys0, ys1,
                pv0, pv1, o1, l1, l0, lane0);
        t1 = pv1;

        xload(xlds, rbase + 3, xb);
        substep(xa, (unsigned)(rbase + 2) < (unsigned)TL, y0, y1, ys0, ys1,
                pv0, pv1, o1, l2, l1, lane0);
        t2 = pv1;

        xload(xlds, rbase + 4, xa);   // next epoch m=0
        substep(xb, (unsigned)(rbase + 3) < (unsigned)TL, y0, y1, ys0, ys1,
                pv0, pv1, o1, l3, l2, lane0);
        t3 = pv1;

        carry = l3;

        if (l == 63 && W < 3)
            *(f32x4*)&pkt[e & 1][W][0] = f32x4{t0, t1, t2, t3};
        __syncthreads();
    }

    if (W == 3 && l == 63) ws[b] = sqrtf(pv1);   // row 511, col 511
}

__global__ void dtw_reduce_kernel(const float* __restrict__ ws, float* __restrict__ out) {
    const int t = threadIdx.x;          // 64 threads
    float v = ws[t] + ws[t + 64];
    #pragma unroll
    for (int d2 = 32; d2 > 0; d2 >>= 1) v += __shfl_down(v, d2);
    if (t == 0) out[0] = v * (1.0f / TNB);
}

extern "C" void kernel_launch(void* const* d_in, const int* in_sizes, int n_in,
                              void* d_out, int out_size, void* d_ws, size_t ws_size,
                              hipStream_t stream) {
    const float* s1 = (const float*)d_in[0];
    const float* s2 = (const float*)d_in[1];
    float* ws  = (float*)d_ws;
    float* out = (float*)d_out;

    dtw_split_kernel<<<TNB, 256, 0, stream>>>(s1, s2, ws);
    dtw_reduce_kernel<<<1, 64, 0, stream>>>(ws, out);
}

// Round 11
// 96.013 us; speedup vs baseline: 2.8473x; 1.2231x over previous
//
#include <hip/hip_runtime.h>
#include <math.h>

// DTW loss: B=128, L1=L2=512, D=16.
// R11: 4-wave column-split skewed systolic (R10 logic) with a REAL pipeline:
//  - x rows prefetched via asm-volatile ds_read_b128 x4 + b32 (cannot be sunk
//    or re-executed -> values stay in VGPRs), ring of 4, depth-3 ahead,
//    counted s_waitcnt lgkmcnt(10) + sched_barrier(0) per substep (rule #18)
//  - XSTR=20 (16B-aligned b128, near-zero bank conflicts per R8)
//  - 8 substeps/epoch, WOFF=71 (71-63=8 -> packet from wave W-1 epoch e-1
//    covers exactly lane0-of-W's 8 rows at epoch e), 99 barriers
//  - freeze-on-invalid (cndmask) instead of sq-poison: fill AND drain safe

#define TL 512
#define TD 16
#define TNB 128
#define BIGF 3.0e38f
#define INFF __builtin_inff()
#define XSTR 20    // floats per padded LDS row (80 B)
#define WOFF 71
#define EP 8
#define NE 99      // ceil((512 + 3*71 + 63 + 1)/8) epochs

typedef float f32x2 __attribute__((ext_vector_type(2)));
typedef float f32x4 __attribute__((ext_vector_type(4)));

__device__ inline f32x2 pk_fma(f32x2 a, f32x2 b, f32x2 c) {
    f32x2 d;
    asm("v_pk_fma_f32 %0, %1, %2, %3" : "=v"(d) : "v"(a), "v"(b), "v"(c));
    return d;
}
__device__ inline f32x2 pk_mul(f32x2 a, f32x2 b) {
    f32x2 d;
    asm("v_pk_mul_f32 %0, %1, %2" : "=v"(d) : "v"(a), "v"(b));
    return d;
}
__device__ inline float min3f(float a, float b, float c) {
    float d;
    asm("v_min3_f32 %0, %1, %2, %3" : "=v"(d) : "v"(a), "v"(b), "v"(c));
    return d;
}
template<int CTRL, int RM, bool BC>
__device__ inline float dpp_mov(float old_, float src) {
    return __int_as_float(__builtin_amdgcn_update_dpp(
        __float_as_int(old_), __float_as_int(src), CTRL, RM, 0xf, BC));
}

struct XR { f32x4 q0, q1, q2, q3; float sq; };

// issue 5 DS reads for (clamped) row r; results land in x's registers and
// MUST NOT be read before the matching lgkmcnt wait
__device__ inline void xissue(unsigned base, int r, XR& x) {
    int rc = r < 0 ? 0 : (r > TL - 1 ? TL - 1 : r);
    unsigned a = base + (unsigned)(rc * (XSTR * 4));
    asm volatile("ds_read_b128 %0, %1 offset:0"  : "=v"(x.q0) : "v"(a));
    asm volatile("ds_read_b128 %0, %1 offset:16" : "=v"(x.q1) : "v"(a));
    asm volatile("ds_read_b128 %0, %1 offset:32" : "=v"(x.q2) : "v"(a));
    asm volatile("ds_read_b128 %0, %1 offset:48" : "=v"(x.q3) : "v"(a));
    asm volatile("ds_read_b32  %0, %1 offset:64" : "=v"(x.sq) : "v"(a));
}

// wait until <=10 DS ops outstanding: drains exactly the substep's buffer
// (5 ops, oldest) while the next two substeps' 10 stay in flight
#define WAITC() { asm volatile("s_waitcnt lgkmcnt(10)" ::: "memory"); \
                  __builtin_amdgcn_sched_barrier(0); }

__device__ inline void sub(const XR& x, int r,
                           const f32x2 (&y0)[8], const f32x2 (&y1)[8],
                           f32x2 ys0, f32x2 ys1,
                           float& pv0, float& pv1, float& o1,
                           float bL, float bD, bool lane0) {
    const f32x2* xd = (const f32x2*)&x;          // q0..q3 as 8 f32x2
    f32x2 a0 = ys0, a1 = ys1;                    // {ysq, 0}; y pre-scaled -2
    #pragma unroll
    for (int k = 0; k < 8; ++k) {
        a0 = pk_fma(xd[k], y0[k], a0);
        a1 = pk_fma(xd[k], y1[k], a1);
    }
    const float c0 = x.sq + (a0.x + a0.y);
    const float c1 = x.sq + (a1.x + a1.y);

    float left = dpp_mov<0x138, 0xf, false>(BIGF, pv1);  // DTW[r][j0-1]
    float diag = dpp_mov<0x138, 0xf, false>(BIGF, o1);   // DTW[r-1][j0-1]
    if (lane0) { left = bL; diag = bD; }
    o1 = pv1;

    const float v0 = c0 + min3f(pv0, left, diag);
    const float v1 = c1 + min3f(pv1, v0, pv0);
    const bool valid = (unsigned)r < (unsigned)TL;
    pv0 = valid ? v0 : pv0;
    pv1 = valid ? v1 : pv1;
}

__global__ __launch_bounds__(256, 1) void dtw_split_kernel(const float* __restrict__ s1,
                                                           const float* __restrict__ s2,
                                                           float* __restrict__ ws) {
    const int b   = blockIdx.x;
    const int tid = threadIdx.x;
    const int W   = tid >> 6;    // wave 0..3
    const int l   = tid & 63;

    __shared__ float xlds[TL * XSTR];   // 40,960 B (16 x-floats + sq per row)
    __shared__ f32x4 pkt[2][4][2];      // 256 B boundary packets (8 rows each)

    const float* s1b = s1 + (size_t)b * TL * TD;

    // stage s1 rows (2/thread) + row sumsq
    #pragma unroll
    for (int q = 0; q < 2; ++q) {
        const int r = 2 * tid + q;
        const f32x4* src = (const f32x4*)(s1b + r * TD);
        f32x4 q0 = src[0], q1 = src[1], q2 = src[2], q3 = src[3];
        f32x4* dst = (f32x4*)(xlds + r * XSTR);
        dst[0] = q0; dst[1] = q1; dst[2] = q2; dst[3] = q3;
        f32x2 a_ = pk_mul(f32x2{q0.x, q0.y}, f32x2{q0.x, q0.y});
        a_ = pk_fma(f32x2{q0.z, q0.w}, f32x2{q0.z, q0.w}, a_);
        a_ = pk_fma(f32x2{q1.x, q1.y}, f32x2{q1.x, q1.y}, a_);
        a_ = pk_fma(f32x2{q1.z, q1.w}, f32x2{q1.z, q1.w}, a_);
        a_ = pk_fma(f32x2{q2.x, q2.y}, f32x2{q2.x, q2.y}, a_);
        a_ = pk_fma(f32x2{q2.z, q2.w}, f32x2{q2.z, q2.w}, a_);
        a_ = pk_fma(f32x2{q3.x, q3.y}, f32x2{q3.x, q3.y}, a_);
        a_ = pk_fma(f32x2{q3.z, q3.w}, f32x2{q3.z, q3.w}, a_);
        xlds[r * XSTR + 16] = a_.x + a_.y;
    }
    if (tid < 64) ((float*)pkt)[tid] = BIGF;

    // y tile: 2 cols/lane; prescale -2; acc seeds {ysq, 0}
    const int j0 = 2 * (64 * W + l);
    f32x2 y0[8], y1[8];
    const float* yp0 = s2 + ((size_t)b * TL + j0) * TD;
    #pragma unroll
    for (int k = 0; k < 8; ++k) {
        y0[k] = *(const f32x2*)(yp0 + 2 * k);
        y1[k] = *(const f32x2*)(yp0 + TD + 2 * k);
    }
    f32x2 s0a = pk_mul(y0[0], y0[0]), s1a = pk_mul(y1[0], y1[0]);
    #pragma unroll
    for (int k = 1; k < 8; ++k) {
        s0a = pk_fma(y0[k], y0[k], s0a);
        s1a = pk_fma(y1[k], y1[k], s1a);
    }
    const f32x2 ys0 = {s0a.x + s0a.y, 0.f};
    const f32x2 ys1 = {s1a.x + s1a.y, 0.f};
    #pragma unroll
    for (int k = 0; k < 8; ++k) {
        y0[k] = pk_mul(y0[k], f32x2{-2.f, -2.f});
        y1[k] = pk_mul(y1[k], f32x2{-2.f, -2.f});
    }

    __syncthreads();

    const unsigned base = (unsigned)(uintptr_t)&xlds[0];  // LDS byte offset
    const int gL = WOFF * W + l;
    const bool lane0 = (l == 0);
    float pv0 = INFF, pv1 = INFF, o1 = INFF;
    float carry = (W == 0) ? 0.f : BIGF;   // lane0 diag seed DTW[-1][-1]=0

    XR x0, x1, x2, x3;
    xissue(base, 0 - gL, x0);
    xissue(base, 1 - gL, x1);
    xissue(base, 2 - gL, x2);

    for (int e = 0; e < NE; ++e) {
        float lb0 = BIGF, lb1 = BIGF, lb2 = BIGF, lb3 = BIGF;
        float lb4 = BIGF, lb5 = BIGF, lb6 = BIGF, lb7 = BIGF;
        if (W > 0) {
            f32x4 pA = pkt[(e + 1) & 1][W - 1][0];
            f32x4 pB = pkt[(e + 1) & 1][W - 1][1];
            lb0 = pA.x; lb1 = pA.y; lb2 = pA.z; lb3 = pA.w;
            lb4 = pB.x; lb5 = pB.y; lb6 = pB.z; lb7 = pB.w;
        }
        const int rb = EP * e - gL;
        float t0, t1, t2, t3, t4, t5, t6, t7;

        WAITC(); xissue(base, rb + 3,  x3);
        sub(x0, rb + 0, y0, y1, ys0, ys1, pv0, pv1, o1, lb0, carry, lane0); t0 = pv1;
        WAITC(); xissue(base, rb + 4,  x0);
        sub(x1, rb + 1, y0, y1, ys0, ys1, pv0, pv1, o1, lb1, lb0, lane0);   t1 = pv1;
        WAITC(); xissue(base, rb + 5,  x1);
        sub(x2, rb + 2, y0, y1, ys0, ys1, pv0, pv1, o1, lb2, lb1, lane0);   t2 = pv1;
        WAITC(); xissue(base, rb + 6,  x2);
        sub(x3, rb + 3, y0, y1, ys0, ys1, pv0, pv1, o1, lb3, lb2, lane0);   t3 = pv1;
        WAITC(); xissue(base, rb + 7,  x3);
        sub(x0, rb + 4, y0, y1, ys0, ys1, pv0, pv1, o1, lb4, lb3, lane0);   t4 = pv1;
        WAITC(); xissue(base, rb + 8,  x0);
        sub(x1, rb + 5, y0, y1, ys0, ys1, pv0, pv1, o1, lb5, lb4, lane0);   t5 = pv1;
        WAITC(); xissue(base, rb + 9,  x1);
        sub(x2, rb + 6, y0, y1, ys0, ys1, pv0, pv1, o1, lb6, lb5, lane0);   t6 = pv1;
        WAITC(); xissue(base, rb + 10, x2);
        sub(x3, rb + 7, y0, y1, ys0, ys1, pv0, pv1, o1, lb7, lb6, lane0);   t7 = pv1;

        carry = lb7;

        if (l == 63 && W < 3) {
            pkt[e & 1][W][0] = f32x4{t0, t1, t2, t3};
            pkt[e & 1][W][1] = f32x4{t4, t5, t6, t7};
        }
        __syncthreads();
    }

    if (W == 3 && l == 63) ws[b] = sqrtf(pv1);   // DTW[511][511]
}

__global__ void dtw_reduce_kernel(const float* __restrict__ ws, float* __restrict__ out) {
    const int t = threadIdx.x;          // 64 threads
    float v = ws[t] + ws[t + 64];
    #pragma unroll
    for (int d2 = 32; d2 > 0; d2 >>= 1) v += __shfl_down(v, d2);
    if (t == 0) out[0] = v * (1.0f / TNB);
}

extern "C" void kernel_launch(void* const* d_in, const int* in_sizes, int n_in,
                              void* d_out, int out_size, void* d_ws, size_t ws_size,
                              hipStream_t stream) {
    const float* s1 = (const float*)d_in[0];
    const float* s2 = (const float*)d_in[1];
    float* ws  = (float*)d_ws;
    float* out = (float*)d_out;

    dtw_split_kernel<<<TNB, 256, 0, stream>>>(s1, s2, ws);
    dtw_reduce_kernel<<<1, 64, 0, stream>>>(ws, out);
}